// Round 8
// baseline (277.583 us; speedup 1.0000x reference)
//
#include <hip/hip_runtime.h>
#include <hip/hip_bf16.h>

typedef __attribute__((ext_vector_type(8))) short short8;
typedef __attribute__((ext_vector_type(4))) short s16x4;
typedef __attribute__((ext_vector_type(4))) float f32x4;

#define AS1 __attribute__((address_space(1)))
#define AS3 __attribute__((address_space(3)))

__device__ __forceinline__ void gload_lds16(const void* g, void* l) {
  __builtin_amdgcn_global_load_lds((const AS1 void*)g, (AS3 void*)l, 16, 0, 0);
}

__device__ __forceinline__ unsigned short f2bf(float f) {
  unsigned int u = __float_as_uint(f);
  u += 0x7fffu + ((u >> 16) & 1u);
  return (unsigned short)(u >> 16);
}

// ---------------- x: fp32 -> bf16, 8 elems/thread ----------------
__global__ __launch_bounds__(256) void k_convert(const float* __restrict__ in,
                                                 unsigned short* __restrict__ out) {
  long i = (long)blockIdx.x * 256 + threadIdx.x;
  const float4* p = (const float4*)in + i * 2;
  float4 a = p[0], b = p[1];
  short8 o;
  o[0] = (short)f2bf(a.x); o[1] = (short)f2bf(a.y);
  o[2] = (short)f2bf(a.z); o[3] = (short)f2bf(a.w);
  o[4] = (short)f2bf(b.x); o[5] = (short)f2bf(b.y);
  o[6] = (short)f2bf(b.z); o[7] = (short)f2bf(b.w);
  ((short8*)out)[i] = o;
}

// ---------- W [K][N] fp32 -> WT [N][K] bf16 (64x64 tiles) ----------
__global__ __launch_bounds__(256) void k_transpose_w(const float* __restrict__ w,
                                                     unsigned short* __restrict__ wt,
                                                     int K, int N) {
  __shared__ float t[64][65];
  const int tilesN = N >> 6;
  const int tk = blockIdx.x / tilesN, tn = blockIdx.x % tilesN;
  const int c = threadIdx.x & 63, r0 = (threadIdx.x >> 6) * 16;
#pragma unroll
  for (int i = 0; i < 16; ++i)
    t[r0 + i][c] = w[(long)(tk * 64 + r0 + i) * N + tn * 64 + c];
  __syncthreads();
#pragma unroll
  for (int i = 0; i < 16; ++i)
    wt[(long)(tn * 64 + r0 + i) * K + tk * 64 + c] = f2bf(t[c][r0 + i]);
}

// ---------- V part of qkv -> VT [bh*64 + d][2048] bf16 ----------
__global__ __launch_bounds__(256) void k_transpose_v(const unsigned short* __restrict__ qkv,
                                                     unsigned short* __restrict__ vt) {
  __shared__ __align__(16) unsigned short t[64][72];
  const int tt = blockIdx.x & 31, bh = blockIdx.x >> 5;
  const int b = bh >> 4, h = bh & 15;
  const int r = threadIdx.x >> 2, c0 = (threadIdx.x & 3) * 16;
  const unsigned short* src = qkv + (long)(b * 2048 + tt * 64 + r) * 3072 + 2048 + h * 64 + c0;
  *(short8*)&t[r][c0] = *(const short8*)src;
  *(short8*)&t[r][c0 + 8] = *(const short8*)(src + 8);
  __syncthreads();
  short8 w0, w1;
#pragma unroll
  for (int i = 0; i < 8; ++i) w0[i] = (short)t[c0 + i][r];
#pragma unroll
  for (int i = 0; i < 8; ++i) w1[i] = (short)t[c0 + 8 + i][r];
  unsigned short* dst = vt + (long)(bh * 64 + r) * 2048 + tt * 64 + c0;
  *(short8*)dst = w0;
  *(short8*)(dst + 8) = w1;
}

// ---------- GEMM: C[M][N] = A[M][K] @ BT[N][K]^T + bias, 128x128 tile ----------
// Counted-vmcnt double-buffer + T2 XOR swizzle + XCD-aware block swizzle.
template <int OUT_BF16>
__global__ __launch_bounds__(256) void k_gemm(const unsigned short* __restrict__ A,
                                              const unsigned short* __restrict__ BT,
                                              const float* __restrict__ bias,
                                              void* __restrict__ out,
                                              int M, int N, int K) {
  __shared__ __align__(16) unsigned short As[2][128 * 64];
  __shared__ __align__(16) unsigned short Bs[2][128 * 64];
  const int tid = threadIdx.x, lane = tid & 63, wid = tid >> 6;
  const int r16 = lane & 15, khi = lane >> 4;
  const int wr = wid >> 1, wc = wid & 1;
  const int tilesN = N >> 7;
  const int cpx = gridDim.x >> 3;  // grid % 8 == 0
  const int bid = ((int)blockIdx.x & 7) * cpx + ((int)blockIdx.x >> 3);
  const int tm = bid / tilesN, tn = bid % tilesN;
  const long m0 = (long)tm * 128, n0 = (long)tn * 128;
  f32x4 acc[4][4] = {};
  const int srow = tid >> 3;
  const int scol = ((tid & 7) ^ (srow & 7)) * 8;
  const unsigned short* aSrc = A + (m0 + srow) * K + scol;
  const unsigned short* bSrc = BT + (n0 + srow) * K + scol;
  unsigned short* aDst = &As[0][0] + tid * 8;
  unsigned short* bDst = &Bs[0][0] + tid * 8;
  const int nk = K >> 6;

#pragma unroll
  for (int call = 0; call < 4; ++call) {
    gload_lds16(aSrc + (long)call * 32 * K, aDst + call * 2048);
    gload_lds16(bSrc + (long)call * 32 * K, bDst + call * 2048);
  }

  int cur = 0;
  for (int ki = 0; ki < nk; ++ki) {
    __builtin_amdgcn_s_barrier();
    if (ki + 1 < nk) {
      const long k0 = (long)(ki + 1) * 64;
#pragma unroll
      for (int call = 0; call < 4; ++call) {
        gload_lds16(aSrc + (long)call * 32 * K + k0, aDst + (cur ^ 1) * 8192 + call * 2048);
        gload_lds16(bSrc + (long)call * 32 * K + k0, bDst + (cur ^ 1) * 8192 + call * 2048);
      }
      asm volatile("s_waitcnt vmcnt(8)" ::: "memory");
    } else {
      asm volatile("s_waitcnt vmcnt(0)" ::: "memory");
    }
    __builtin_amdgcn_s_barrier();
    __builtin_amdgcn_s_setprio(1);
#pragma unroll
    for (int kk = 0; kk < 2; ++kk) {
      const int pc = ((kk * 4 + khi) ^ (r16 & 7)) * 8;
      short8 af[4], bf[4];
#pragma unroll
      for (int m = 0; m < 4; ++m)
        af[m] = *(const short8*)&As[cur][(wr * 64 + m * 16 + r16) * 64 + pc];
#pragma unroll
      for (int n = 0; n < 4; ++n)
        bf[n] = *(const short8*)&Bs[cur][(wc * 64 + n * 16 + r16) * 64 + pc];
#pragma unroll
      for (int m = 0; m < 4; ++m)
#pragma unroll
        for (int n = 0; n < 4; ++n)
          acc[m][n] = __builtin_amdgcn_mfma_f32_16x16x32_bf16(af[m], bf[n], acc[m][n], 0, 0, 0);
    }
    __builtin_amdgcn_s_setprio(0);
    cur ^= 1;
  }
#pragma unroll
  for (int m = 0; m < 4; ++m) {
    long row = m0 + wr * 64 + m * 16 + khi * 4;
#pragma unroll
    for (int n = 0; n < 4; ++n) {
      int col = (int)n0 + wc * 64 + n * 16 + r16;
      float bv = bias[col];
#pragma unroll
      for (int j = 0; j < 4; ++j) {
        float v = acc[m][n][j] + bv;
        if (OUT_BF16)
          ((unsigned short*)out)[(row + j) * N + col] = f2bf(v);
        else
          ((float*)out)[(row + j) * N + col] = v;
      }
    }
  }
}

// ---------- causal flash attention, QBLK=128, KVBLK=64, HDIM=64 ----------
// Round-6 structure. Softmax in log2 domain (exp2, scale folded); P-pack via
// native float->bf16 casts (compiler fuses to v_cvt_pk_bf16_f32 per m240).
__global__ __launch_bounds__(512) void k_attn(const unsigned short* __restrict__ qkv,
                                              const unsigned short* __restrict__ vt,
                                              unsigned short* __restrict__ aout) {
  __shared__ __align__(16) unsigned short Ks[2][64 * 64];
  __shared__ __align__(16) unsigned short VTs[2][64 * 64];
  __shared__ __align__(16) unsigned short Ps[8][16 * 72];
  const int tid = threadIdx.x, lane = tid & 63, wid = tid >> 6;
  const int r16 = lane & 15, khi = lane >> 4;
  const int qt = 15 - (int)(blockIdx.x >> 6), bh = blockIdx.x & 63;
  const int b = bh >> 4, h = bh & 15;
  const long qrow0 = (long)b * 2048 + qt * 128;

  const int srow = wid * 8 + (lane >> 3);
  const int lck = (lane & 7) ^ (srow & 7);
  const unsigned short* kbase =
      qkv + ((long)b * 2048 + srow) * 3072 + 1024 + h * 64 + lck * 8;
  const unsigned short* vbase = vt + ((long)bh * 64 + srow) * 2048 + lck * 8;

  const long qrow = qrow0 + wid * 16 + r16;
  const short8 qf0 = *(const short8*)&qkv[qrow * 3072 + h * 64 + khi * 8];
  const short8 qf1 = *(const short8*)&qkv[qrow * 3072 + h * 64 + 32 + khi * 8];

  gload_lds16(kbase, &Ks[0][wid * 512]);
  gload_lds16(vbase, &VTs[0][wid * 512]);

  const int ktmax = 2 * qt + 1;
  const int ktw = (qt * 128 + wid * 16 + 15) >> 6;
  const int qg = qt * 128 + wid * 16 + r16;
  const float SC = 0.18033688f;  // 0.125 * log2(e)
  float m_run = -1e30f, l_run = 0.f;
  f32x4 o[4] = {};

  for (int kt = 0; kt <= ktmax; ++kt) {
    const int cur = kt & 1;
    __builtin_amdgcn_s_barrier();  // all waves done reading buf[cur^1]
    if (kt < ktmax) {
      gload_lds16(kbase + (long)(kt + 1) * 64 * 3072, &Ks[cur ^ 1][wid * 512]);
      gload_lds16(vbase + (kt + 1) * 64, &VTs[cur ^ 1][wid * 512]);
      asm volatile("s_waitcnt vmcnt(2)" ::: "memory");
    } else {
      asm volatile("s_waitcnt vmcnt(0)" ::: "memory");
    }
    __builtin_amdgcn_s_barrier();  // buf[cur] visible
    if (kt > ktw) continue;

    // S^T = mfma(K, Q): lane holds q = r16, k = 16n + khi*4 + j
    f32x4 s[4] = {};
    __builtin_amdgcn_s_setprio(1);
#pragma unroll
    for (int kk = 0; kk < 2; ++kk) {
      const int pc = ((kk * 4 + khi) ^ (r16 & 7)) * 8;
      const short8 qf = kk ? qf1 : qf0;
#pragma unroll
      for (int n = 0; n < 4; ++n) {
        short8 kf = *(const short8*)&Ks[cur][(n * 16 + r16) * 64 + pc];
        s[n] = __builtin_amdgcn_mfma_f32_16x16x32_bf16(kf, qf, s[n], 0, 0, 0);
      }
    }
    __builtin_amdgcn_s_setprio(0);

    // scale into log2 domain + causal mask
    const bool need_mask = (kt * 64 + 63) > (qt * 128 + wid * 16);
    const int ktB = kt * 64;
#pragma unroll
    for (int n = 0; n < 4; ++n)
#pragma unroll
      for (int j = 0; j < 4; ++j) {
        float v = s[n][j] * SC;
        if (need_mask && (ktB + n * 16 + khi * 4 + j) > qg) v = -1e30f;
        s[n][j] = v;
      }

    // online softmax (log2 domain): row max = 15 in-lane fmax + 2 shfl
    float pm = s[0][0];
#pragma unroll
    for (int n = 0; n < 4; ++n)
#pragma unroll
      for (int j = 0; j < 4; ++j) pm = fmaxf(pm, s[n][j]);
    pm = fmaxf(pm, __shfl_xor(pm, 16, 64));
    pm = fmaxf(pm, __shfl_xor(pm, 32, 64));
    const float mn = fmaxf(m_run, pm);
    const float alpha = exp2f(m_run - mn);
    m_run = mn;
    float rs = 0.f;
#pragma unroll
    for (int n = 0; n < 4; ++n)
#pragma unroll
      for (int j = 0; j < 4; ++j) {
        float e = exp2f(s[n][j] - mn);
        s[n][j] = e;
        rs += e;
      }
    rs += __shfl_xor(rs, 16, 64);
    rs += __shfl_xor(rs, 32, 64);
    l_run = l_run * alpha + rs;
#pragma unroll
    for (int n = 0; n < 4; ++n)
#pragma unroll
      for (int j = 0; j < 4; ++j) o[n][j] *= alpha;

    // P -> LDS bf16: native casts, compiler fuses to v_cvt_pk_bf16_f32 (m240)
#pragma unroll
    for (int n = 0; n < 4; ++n) {
      float2 f01 = {s[n][0], s[n][1]};
      float2 f23 = {s[n][2], s[n][3]};
      __hip_bfloat162 p01 = __float22bfloat162_rn(f01);
      __hip_bfloat162 p23 = __float22bfloat162_rn(f23);
      uint2 pw = {*(unsigned int*)&p01, *(unsigned int*)&p23};
      *(uint2*)&Ps[wid][r16 * 72 + n * 16 + khi * 4] = pw;
    }

    // O^T += mfma(VT, P)
    __builtin_amdgcn_s_setprio(1);
#pragma unroll
    for (int kk = 0; kk < 2; ++kk) {
      const short8 pf = *(const short8*)&Ps[wid][r16 * 72 + kk * 32 + khi * 8];
      const int pc = ((kk * 4 + khi) ^ (r16 & 7)) * 8;
#pragma unroll
      for (int n = 0; n < 4; ++n) {
        short8 vf = *(const short8*)&VTs[cur][(n * 16 + r16) * 64 + pc];
        o[n] = __builtin_amdgcn_mfma_f32_16x16x32_bf16(vf, pf, o[n], 0, 0, 0);
      }
    }
    __builtin_amdgcn_s_setprio(0);
  }

  // epilogue
  const float inv = 1.f / l_run;
#pragma unroll
  for (int n = 0; n < 4; ++n) {
    s16x4 ow;
#pragma unroll
    for (int j = 0; j < 4; ++j) ow[j] = (short)f2bf(o[n][j] * inv);
    *(s16x4*)&aout[qrow * 1024 + h * 64 + n * 16 + khi * 4] = ow;
  }
}

extern "C" void kernel_launch(void* const* d_in, const int* in_sizes, int n_in,
                              void* d_out, int out_size, void* d_ws, size_t ws_size,
                              hipStream_t stream) {
  (void)in_sizes; (void)n_in; (void)out_size; (void)ws_size;
  const float* x = (const float*)d_in[0];
  const float* Wqkv = (const float*)d_in[1];
  const float* bqkv = (const float*)d_in[2];
  const float* Wout = (const float*)d_in[3];
  const float* bout = (const float*)d_in[4];
  char* ws = (char*)d_ws;
  // Buffer plan (peak 88 MB):
  //   xb    [8192][1024] bf16 @ 0        (16 MB)  -- dead after GEMM1; aout aliases it
  //   wqkvt [3072][1024] bf16 @ 16 MB    ( 6 MB)
  //   woutt [1024][1024] bf16 @ 22 MB    ( 2 MB)
  //   qkv   [8192][3072] bf16 @ 24 MB    (48 MB)
  //   vt    [4096][2048] bf16 @ 72 MB    (16 MB)
  unsigned short* xb    = (unsigned short*)(ws + 0);
  unsigned short* wqkvt = (unsigned short*)(ws + (16l << 20));
  unsigned short* woutt = (unsigned short*)(ws + (22l << 20));
  unsigned short* qkv   = (unsigned short*)(ws + (24l << 20));
  unsigned short* vt    = (unsigned short*)(ws + (72l << 20));
  unsigned short* aout  = xb;  // alias: xb dead after GEMM1

  k_convert<<<4096, 256, 0, stream>>>(x, xb);
  k_transpose_w<<<768, 256, 0, stream>>>(Wqkv, wqkvt, 1024, 3072);
  k_transpose_w<<<256, 256, 0, stream>>>(Wout, woutt, 1024, 1024);
  k_gemm<1><<<64 * 24, 256, 0, stream>>>(xb, wqkvt, bqkv, qkv, 8192, 3072, 1024);
  k_transpose_v<<<2048, 256, 0, stream>>>(qkv, vt);
  k_attn<<<16 * 64, 512, 0, stream>>>(qkv, vt, aout);
  k_gemm<0><<<64 * 8, 256, 0, stream>>>(aout, woutt, bout, d_out, 8192, 1024, 1024);
}

// Round 9
// 247.866 us; speedup vs baseline: 1.1199x; 1.1199x over previous
//
#include <hip/hip_runtime.h>

typedef __attribute__((ext_vector_type(8))) short short8;
typedef __attribute__((ext_vector_type(4))) short s16x4;
typedef __attribute__((ext_vector_type(4))) float f32x4;

#define AS1 __attribute__((address_space(1)))
#define AS3 __attribute__((address_space(3)))

__device__ __forceinline__ void gload_lds16(const void* g, void* l) {
  __builtin_amdgcn_global_load_lds((const AS1 void*)g, (AS3 void*)l, 16, 0, 0);
}

__device__ __forceinline__ unsigned short f2bf(float f) {
  unsigned int u = __float_as_uint(f);
  u += 0x7fffu + ((u >> 16) & 1u);
  return (unsigned short)(u >> 16);
}

// ---------------- x: fp32 -> bf16, 8 elems/thread ----------------
__global__ __launch_bounds__(256) void k_convert(const float* __restrict__ in,
                                                 unsigned short* __restrict__ out) {
  long i = (long)blockIdx.x * 256 + threadIdx.x;
  const float4* p = (const float4*)in + i * 2;
  float4 a = p[0], b = p[1];
  short8 o;
  o[0] = (short)f2bf(a.x); o[1] = (short)f2bf(a.y);
  o[2] = (short)f2bf(a.z); o[3] = (short)f2bf(a.w);
  o[4] = (short)f2bf(b.x); o[5] = (short)f2bf(b.y);
  o[6] = (short)f2bf(b.z); o[7] = (short)f2bf(b.w);
  ((short8*)out)[i] = o;
}

// ---------- W [K][N] fp32 -> WT [N][K] bf16 (64x64 tiles) ----------
__global__ __launch_bounds__(256) void k_transpose_w(const float* __restrict__ w,
                                                     unsigned short* __restrict__ wt,
                                                     int K, int N) {
  __shared__ float t[64][65];
  const int tilesN = N >> 6;
  const int tk = blockIdx.x / tilesN, tn = blockIdx.x % tilesN;
  const int c = threadIdx.x & 63, r0 = (threadIdx.x >> 6) * 16;
#pragma unroll
  for (int i = 0; i < 16; ++i)
    t[r0 + i][c] = w[(long)(tk * 64 + r0 + i) * N + tn * 64 + c];
  __syncthreads();
#pragma unroll
  for (int i = 0; i < 16; ++i)
    wt[(long)(tn * 64 + r0 + i) * K + tk * 64 + c] = f2bf(t[c][r0 + i]);
}

// ---------- V part of qkv -> VT [bh*64 + d][2048] bf16 ----------
__global__ __launch_bounds__(256) void k_transpose_v(const unsigned short* __restrict__ qkv,
                                                     unsigned short* __restrict__ vt) {
  __shared__ __align__(16) unsigned short t[64][72];
  const int tt = blockIdx.x & 31, bh = blockIdx.x >> 5;
  const int b = bh >> 4, h = bh & 15;
  const int r = threadIdx.x >> 2, c0 = (threadIdx.x & 3) * 16;
  const unsigned short* src = qkv + (long)(b * 2048 + tt * 64 + r) * 3072 + 2048 + h * 64 + c0;
  *(short8*)&t[r][c0] = *(const short8*)src;
  *(short8*)&t[r][c0 + 8] = *(const short8*)(src + 8);
  __syncthreads();
  short8 w0, w1;
#pragma unroll
  for (int i = 0; i < 8; ++i) w0[i] = (short)t[c0 + i][r];
#pragma unroll
  for (int i = 0; i < 8; ++i) w1[i] = (short)t[c0 + 8 + i][r];
  unsigned short* dst = vt + (long)(bh * 64 + r) * 2048 + tt * 64 + c0;
  *(short8*)dst = w0;
  *(short8*)(dst + 8) = w1;
}

// ---------- GEMM: C[M][N] = A[M][K] @ BT[N][K]^T + bias, 128x128 tile ----------
// Counted-vmcnt double-buffer + T2 XOR swizzle + XCD-aware block swizzle.
template <int OUT_BF16>
__global__ __launch_bounds__(256) void k_gemm(const unsigned short* __restrict__ A,
                                              const unsigned short* __restrict__ BT,
                                              const float* __restrict__ bias,
                                              void* __restrict__ out,
                                              int M, int N, int K) {
  __shared__ __align__(16) unsigned short As[2][128 * 64];
  __shared__ __align__(16) unsigned short Bs[2][128 * 64];
  const int tid = threadIdx.x, lane = tid & 63, wid = tid >> 6;
  const int r16 = lane & 15, khi = lane >> 4;
  const int wr = wid >> 1, wc = wid & 1;
  const int tilesN = N >> 7;
  const int cpx = gridDim.x >> 3;  // grid % 8 == 0
  const int bid = ((int)blockIdx.x & 7) * cpx + ((int)blockIdx.x >> 3);
  const int tm = bid / tilesN, tn = bid % tilesN;
  const long m0 = (long)tm * 128, n0 = (long)tn * 128;
  f32x4 acc[4][4] = {};
  const int srow = tid >> 3;
  const int scol = ((tid & 7) ^ (srow & 7)) * 8;
  const unsigned short* aSrc = A + (m0 + srow) * K + scol;
  const unsigned short* bSrc = BT + (n0 + srow) * K + scol;
  unsigned short* aDst = &As[0][0] + tid * 8;
  unsigned short* bDst = &Bs[0][0] + tid * 8;
  const int nk = K >> 6;

#pragma unroll
  for (int call = 0; call < 4; ++call) {
    gload_lds16(aSrc + (long)call * 32 * K, aDst + call * 2048);
    gload_lds16(bSrc + (long)call * 32 * K, bDst + call * 2048);
  }

  int cur = 0;
  for (int ki = 0; ki < nk; ++ki) {
    __builtin_amdgcn_s_barrier();
    if (ki + 1 < nk) {
      const long k0 = (long)(ki + 1) * 64;
#pragma unroll
      for (int call = 0; call < 4; ++call) {
        gload_lds16(aSrc + (long)call * 32 * K + k0, aDst + (cur ^ 1) * 8192 + call * 2048);
        gload_lds16(bSrc + (long)call * 32 * K + k0, bDst + (cur ^ 1) * 8192 + call * 2048);
      }
      asm volatile("s_waitcnt vmcnt(8)" ::: "memory");
    } else {
      asm volatile("s_waitcnt vmcnt(0)" ::: "memory");
    }
    __builtin_amdgcn_s_barrier();
    __builtin_amdgcn_s_setprio(1);
#pragma unroll
    for (int kk = 0; kk < 2; ++kk) {
      const int pc = ((kk * 4 + khi) ^ (r16 & 7)) * 8;
      short8 af[4], bf[4];
#pragma unroll
      for (int m = 0; m < 4; ++m)
        af[m] = *(const short8*)&As[cur][(wr * 64 + m * 16 + r16) * 64 + pc];
#pragma unroll
      for (int n = 0; n < 4; ++n)
        bf[n] = *(const short8*)&Bs[cur][(wc * 64 + n * 16 + r16) * 64 + pc];
#pragma unroll
      for (int m = 0; m < 4; ++m)
#pragma unroll
        for (int n = 0; n < 4; ++n)
          acc[m][n] = __builtin_amdgcn_mfma_f32_16x16x32_bf16(af[m], bf[n], acc[m][n], 0, 0, 0);
    }
    __builtin_amdgcn_s_setprio(0);
    cur ^= 1;
  }
#pragma unroll
  for (int m = 0; m < 4; ++m) {
    long row = m0 + wr * 64 + m * 16 + khi * 4;
#pragma unroll
    for (int n = 0; n < 4; ++n) {
      int col = (int)n0 + wc * 64 + n * 16 + r16;
      float bv = bias[col];
#pragma unroll
      for (int j = 0; j < 4; ++j) {
        float v = acc[m][n][j] + bv;
        if (OUT_BF16)
          ((unsigned short*)out)[(row + j) * N + col] = f2bf(v);
        else
          ((float*)out)[(row + j) * N + col] = v;
      }
    }
  }
}

// ---------- causal flash attention, QBLK=128, KVBLK=64, HDIM=64 ----------
// R6 structure. Softmax: raw-domain max, scale folded into fma, hardware
// exp2 (__builtin_amdgcn_exp2f), exact skip-rescale vote, truncating
// v_perm P-pack (P in [0,1], positive -> truncation safe).
__global__ __launch_bounds__(512) void k_attn(const unsigned short* __restrict__ qkv,
                                              const unsigned short* __restrict__ vt,
                                              unsigned short* __restrict__ aout) {
  __shared__ __align__(16) unsigned short Ks[2][64 * 64];
  __shared__ __align__(16) unsigned short VTs[2][64 * 64];
  __shared__ __align__(16) unsigned short Ps[8][16 * 72];
  const int tid = threadIdx.x, lane = tid & 63, wid = tid >> 6;
  const int r16 = lane & 15, khi = lane >> 4;
  const int qt = 15 - (int)(blockIdx.x >> 6), bh = blockIdx.x & 63;
  const int b = bh >> 4, h = bh & 15;
  const long qrow0 = (long)b * 2048 + qt * 128;

  const int srow = wid * 8 + (lane >> 3);
  const int lck = (lane & 7) ^ (srow & 7);
  const unsigned short* kbase =
      qkv + ((long)b * 2048 + srow) * 3072 + 1024 + h * 64 + lck * 8;
  const unsigned short* vbase = vt + ((long)bh * 64 + srow) * 2048 + lck * 8;

  const long qrow = qrow0 + wid * 16 + r16;
  const short8 qf0 = *(const short8*)&qkv[qrow * 3072 + h * 64 + khi * 8];
  const short8 qf1 = *(const short8*)&qkv[qrow * 3072 + h * 64 + 32 + khi * 8];

  gload_lds16(kbase, &Ks[0][wid * 512]);
  gload_lds16(vbase, &VTs[0][wid * 512]);

  const int ktmax = 2 * qt + 1;
  const int ktw = (qt * 128 + wid * 16 + 15) >> 6;
  const int qg = qt * 128 + wid * 16 + r16;
  const float SC = 0.18033688f;  // 0.125 * log2(e)
  float m_run = -1e30f, l_run = 0.f;
  f32x4 o[4] = {};

  for (int kt = 0; kt <= ktmax; ++kt) {
    const int cur = kt & 1;
    __builtin_amdgcn_s_barrier();  // all waves done reading buf[cur^1]
    if (kt < ktmax) {
      gload_lds16(kbase + (long)(kt + 1) * 64 * 3072, &Ks[cur ^ 1][wid * 512]);
      gload_lds16(vbase + (kt + 1) * 64, &VTs[cur ^ 1][wid * 512]);
      asm volatile("s_waitcnt vmcnt(2)" ::: "memory");
    } else {
      asm volatile("s_waitcnt vmcnt(0)" ::: "memory");
    }
    __builtin_amdgcn_s_barrier();  // buf[cur] visible
    if (kt > ktw) continue;

    // S^T = mfma(K, Q): lane holds q = r16, k = 16n + khi*4 + j (RAW scores)
    f32x4 s[4] = {};
    __builtin_amdgcn_s_setprio(1);
#pragma unroll
    for (int kk = 0; kk < 2; ++kk) {
      const int pc = ((kk * 4 + khi) ^ (r16 & 7)) * 8;
      const short8 qf = kk ? qf1 : qf0;
#pragma unroll
      for (int n = 0; n < 4; ++n) {
        short8 kf = *(const short8*)&Ks[cur][(n * 16 + r16) * 64 + pc];
        s[n] = __builtin_amdgcn_mfma_f32_16x16x32_bf16(kf, qf, s[n], 0, 0, 0);
      }
    }
    __builtin_amdgcn_s_setprio(0);

    // causal mask in raw domain (diagonal-region waves only; wave-uniform)
    const bool need_mask = (kt * 64 + 63) > (qt * 128 + wid * 16);
    if (need_mask) {
      const int ktB = kt * 64;
#pragma unroll
      for (int n = 0; n < 4; ++n)
#pragma unroll
        for (int j = 0; j < 4; ++j)
          if ((ktB + n * 16 + khi * 4 + j) > qg) s[n][j] = -1e30f;
    }

    // row max on raw scores (balanced tree) + 2 shfl; scale once
    float pmn[4];
#pragma unroll
    for (int n = 0; n < 4; ++n)
      pmn[n] = fmaxf(fmaxf(s[n][0], s[n][1]), fmaxf(s[n][2], s[n][3]));
    float pm = fmaxf(fmaxf(pmn[0], pmn[1]), fmaxf(pmn[2], pmn[3]));
    pm = fmaxf(pm, __shfl_xor(pm, 16, 64));
    pm = fmaxf(pm, __shfl_xor(pm, 32, 64));
    const float pmS = pm * SC;
    const float mn = fmaxf(m_run, pmS);
    if (!__all(pmS <= m_run)) {  // exact: skipping when true is identity
      const float alpha = __builtin_amdgcn_exp2f(m_run - mn);
      l_run *= alpha;
#pragma unroll
      for (int n = 0; n < 4; ++n)
#pragma unroll
        for (int j = 0; j < 4; ++j) o[n][j] *= alpha;
    }
    m_run = mn;

    // e = 2^(s*SC - mn) via fma + v_exp; pack P by truncation (v_perm)
    const float nmn = -mn;
    float rsum = 0.f;
    unsigned int pk[8];
#pragma unroll
    for (int n = 0; n < 4; ++n) {
      float e0 = __builtin_amdgcn_exp2f(fmaf(s[n][0], SC, nmn));
      float e1 = __builtin_amdgcn_exp2f(fmaf(s[n][1], SC, nmn));
      float e2 = __builtin_amdgcn_exp2f(fmaf(s[n][2], SC, nmn));
      float e3 = __builtin_amdgcn_exp2f(fmaf(s[n][3], SC, nmn));
      rsum += (e0 + e1) + (e2 + e3);
      pk[n * 2] = __builtin_amdgcn_perm(__float_as_uint(e1), __float_as_uint(e0), 0x07060302u);
      pk[n * 2 + 1] = __builtin_amdgcn_perm(__float_as_uint(e3), __float_as_uint(e2), 0x07060302u);
    }
    rsum += __shfl_xor(rsum, 16, 64);
    rsum += __shfl_xor(rsum, 32, 64);
    l_run += rsum;

    // P -> LDS (wave-local rows)
#pragma unroll
    for (int n = 0; n < 4; ++n) {
      uint2 pw = {pk[n * 2], pk[n * 2 + 1]};
      *(uint2*)&Ps[wid][r16 * 72 + n * 16 + khi * 4] = pw;
    }

    // O^T += mfma(VT, P)
    __builtin_amdgcn_s_setprio(1);
#pragma unroll
    for (int kk = 0; kk < 2; ++kk) {
      const short8 pf = *(const short8*)&Ps[wid][r16 * 72 + kk * 32 + khi * 8];
      const int pc = ((kk * 4 + khi) ^ (r16 & 7)) * 8;
#pragma unroll
      for (int n = 0; n < 4; ++n) {
        short8 vf = *(const short8*)&VTs[cur][(n * 16 + r16) * 64 + pc];
        o[n] = __builtin_amdgcn_mfma_f32_16x16x32_bf16(vf, pf, o[n], 0, 0, 0);
      }
    }
    __builtin_amdgcn_s_setprio(0);
  }

  // epilogue
  const float inv = 1.f / l_run;
#pragma unroll
  for (int n = 0; n < 4; ++n) {
    s16x4 ow;
#pragma unroll
    for (int j = 0; j < 4; ++j) ow[j] = (short)f2bf(o[n][j] * inv);
    *(s16x4*)&aout[qrow * 1024 + h * 64 + n * 16 + khi * 4] = ow;
  }
}

extern "C" void kernel_launch(void* const* d_in, const int* in_sizes, int n_in,
                              void* d_out, int out_size, void* d_ws, size_t ws_size,
                              hipStream_t stream) {
  (void)in_sizes; (void)n_in; (void)out_size; (void)ws_size;
  const float* x = (const float*)d_in[0];
  const float* Wqkv = (const float*)d_in[1];
  const float* bqkv = (const float*)d_in[2];
  const float* Wout = (const float*)d_in[3];
  const float* bout = (const float*)d_in[4];
  char* ws = (char*)d_ws;
  // Buffer plan (peak 88 MB):
  //   xb    [8192][1024] bf16 @ 0        (16 MB)  -- dead after GEMM1; aout aliases it
  //   wqkvt [3072][1024] bf16 @ 16 MB    ( 6 MB)
  //   woutt [1024][1024] bf16 @ 22 MB    ( 2 MB)
  //   qkv   [8192][3072] bf16 @ 24 MB    (48 MB)
  //   vt    [4096][2048] bf16 @ 72 MB    (16 MB)
  unsigned short* xb    = (unsigned short*)(ws + 0);
  unsigned short* wqkvt = (unsigned short*)(ws + (16l << 20));
  unsigned short* woutt = (unsigned short*)(ws + (22l << 20));
  unsigned short* qkv   = (unsigned short*)(ws + (24l << 20));
  unsigned short* vt    = (unsigned short*)(ws + (72l << 20));
  unsigned short* aout  = xb;  // alias: xb dead after GEMM1

  k_convert<<<4096, 256, 0, stream>>>(x, xb);
  k_transpose_w<<<768, 256, 0, stream>>>(Wqkv, wqkvt, 1024, 3072);
  k_transpose_w<<<256, 256, 0, stream>>>(Wout, woutt, 1024, 1024);
  k_gemm<1><<<64 * 24, 256, 0, stream>>>(xb, wqkvt, bqkv, qkv, 8192, 3072, 1024);
  k_transpose_v<<<2048, 256, 0, stream>>>(qkv, vt);
  k_attn<<<16 * 64, 512, 0, stream>>>(qkv, vt, aout);
  k_gemm<0><<<64 * 8, 256, 0, stream>>>(aout, woutt, bout, d_out, 8192, 1024, 1024);
}